// Round 4
// baseline (405.691 us; speedup 1.0000x reference)
//
#include <hip/hip_runtime.h>

// EdgeFeatGAE: 2-layer GCN (R=4 relations share x, W1, W2), out = sum over
// embed dim -> [R, N].
// Algebra: layer2 collapses to scalar per node (wrow[j] = sum_k W2[j][k]);
// H0 = x@W1 is relation-independent; q[i] = dinv_i * g_i makes layer2 a pure
// scalar gather: out_i = dinv_i*(sum_src q[src] + q[i]) + sum(b2).
// R3: radix-partition into 512-node dst buckets (coalesced writes).
// R5: pack 16 records per wave gather instr (4 lanes x 16B fp16 row chunks),
// exact CSR via per-bucket counting sort, register accumulation. 1738->510us.
// R6/7: k_gemm_h0 vectorized (scalar-load-issue bound). 510->481us.
// R8: dynamic bucket cursors kill hist+scan kernels; in-LDS sort. 481->467us.
// R9: k_scat2 occupancy: CH 8192->4096 -> 6 blocks/CU. 467->436us.
// R10: packed-fp16 acc FAILED (latency-bound, cvt on dep chain). 434us.
// R11: k_l1 fp32 acc, 16 lanes/node -> 4 node-chains/wave. 436->399us.
// R12: pre-scaled rows Hsc = dinv*H0 (fp16): layer1 = pure add-gather,
// packed v_pk_add_f16 acc (safe: absmax pinned at 2^-8 storage floor).
// k_l1 86.5->75.4us but VALUBusy 48->37%: now LATENCY-EXPOSED - chain is
// off/cnt(600cy) -> ssrc(600) -> gather(600) with only ~6 waves/SIMD.
// R13: (a) fixedsrc[ri*16]: first-16 adjacency prefix at STATIC address
// (copied in k_scale) -> window-0 chain = fixed->gather (1200cy); window-1
// ssrc prefetched before window-0 processing overlaps the rest. Same in
// k_l2. (b) k_gemm_h0 read x 4x (204MB for 51MB input): shuffle-quarter
// scheme - each thread loads 128B quarter, exchanges k via __shfl width-4.

constexpr int N    = 100000;
constexpr int E    = 1600000;
constexpr int R    = 4;
constexpr int FEAT = 128;
constexpr int HID  = 32;
constexpr int EMB  = 16;
constexpr int M    = R * N;
constexpr int BS   = 256;
constexpr int SH    = 9;                          // bucket = dst >> 9
constexpr int BSPAN = 1 << SH;                    // 512 nodes per bucket
constexpr int NBUCK = (N + BSPAN - 1) / BSPAN;    // 196 buckets per relation
constexpr int CH    = 4096;                       // edges per partition block (R9)
constexpr int NBKr  = (E + CH - 1) / CH;          // 391 blocks per relation
constexpr int RB    = R * NBUCK;                  // 784 buckets total
constexpr int CAP   = 8960;                       // bucket capacity (mean 8192 + 8.5 sigma)
constexpr int FIX   = 16;                         // fixed adjacency prefix (R13)

typedef _Float16 half8 __attribute__((ext_vector_type(8)));   // 16B chunk
typedef _Float16 half2v __attribute__((ext_vector_type(2)));  // packed pair

// ---------------- H0 = x @ W1  [N,32] -> fp16 ----------------
// R13: 4 threads/node, each loads ONE 128B quarter of the x row; k-values
// exchanged via width-4 shuffles. x traffic 204MB -> 51MB.
__global__ void k_gemm_h0(const float* __restrict__ x, const float* __restrict__ W1,
                          _Float16* __restrict__ H0h) {
    int t = blockIdx.x * blockDim.x + threadIdx.x;
    if (t >= N * 4) return;
    int i = t >> 2;            // node
    int qd = t & 3;            // quarter owned + j-octet: j = qd*8
    const float4* xq = (const float4*)(x + (size_t)i * FEAT + qd * 32);
    float4 xv[8];
#pragma unroll
    for (int m = 0; m < 8; ++m) xv[m] = xq[m];    // own 128B quarter
    float acc[8];
#pragma unroll
    for (int kk = 0; kk < 8; ++kk) acc[kk] = 0.f;
#pragma unroll
    for (int qq = 0; qq < 4; ++qq) {              // source quarter
#pragma unroll
        for (int m = 0; m < 8; ++m) {
            float4 v = xv[m];
            float xs[4];
            xs[0] = __shfl(v.x, qq, 4);
            xs[1] = __shfl(v.y, qq, 4);
            xs[2] = __shfl(v.z, qq, 4);
            xs[3] = __shfl(v.w, qq, 4);
            const float* wb = W1 + (qq * 32 + m * 4) * HID + (qd << 3);
#pragma unroll
            for (int dk = 0; dk < 4; ++dk) {
                float4 wlo = *(const float4*)(wb + dk * HID);
                float4 whi = *(const float4*)(wb + dk * HID + 4);
                acc[0] = fmaf(xs[dk], wlo.x, acc[0]);
                acc[1] = fmaf(xs[dk], wlo.y, acc[1]);
                acc[2] = fmaf(xs[dk], wlo.z, acc[2]);
                acc[3] = fmaf(xs[dk], wlo.w, acc[3]);
                acc[4] = fmaf(xs[dk], whi.x, acc[4]);
                acc[5] = fmaf(xs[dk], whi.y, acc[5]);
                acc[6] = fmaf(xs[dk], whi.z, acc[6]);
                acc[7] = fmaf(xs[dk], whi.w, acc[7]);
            }
        }
    }
    half8 hv;
#pragma unroll
    for (int kk = 0; kk < 8; ++kk) hv[kk] = (_Float16)acc[kk];
    ((half8*)H0h)[i * 4 + qd] = hv;    // 16B store, coalesced across lanes
}

// ---------------- wrow[j] = sum_k W2[j][k]; wrowbuf[32] = sum(b2) ----------
__global__ void k_wrow(const float* __restrict__ W2, const float* __restrict__ b2,
                       float* __restrict__ wrowbuf) {
    int j = threadIdx.x;
    if (j < HID) {
        float s = 0.f;
#pragma unroll
        for (int k = 0; k < EMB; ++k) s += W2[j * EMB + k];
        wrowbuf[j] = s;
    } else if (j == HID) {
        float s = 0.f;
#pragma unroll
        for (int k = 0; k < EMB; ++k) s += b2[k];
        wrowbuf[HID] = s;
    }
}

// ---------------- partition: LDS-staged, dynamic bucket-cursor reservation --
__global__ void k_scat2(const int* __restrict__ eis, int* __restrict__ gcur,
                        int* __restrict__ binned) {
    __shared__ int hist[NBUCK], lstart[NBUCK], cursor[NBUCK], gbase[NBUCK];
    __shared__ int wpart[BS / 64];
    __shared__ int shuf[CH];              // 16 KB (R9)
    __shared__ unsigned char bkt[CH];     // 4 KB
    int r = blockIdx.x / NBKr, k = blockIdx.x - r * NBKr;
    const int* srcp = eis + (size_t)r * 2 * E;
    const int* dstp = srcp + E;
    int e0 = k * CH, n = min(CH, E - e0);
    for (int b = threadIdx.x; b < NBUCK; b += BS) hist[b] = 0;
    __syncthreads();
    for (int i = threadIdx.x; i < n; i += BS)
        atomicAdd(&hist[dstp[e0 + i] >> SH], 1);
    __syncthreads();
    // exclusive prefix over NBUCK (<= BS) entries: wave shfl scan (R12)
    int v = (threadIdx.x < NBUCK) ? hist[threadIdx.x] : 0;
    int lanei = threadIdx.x & 63;
    int s = v;
#pragma unroll
    for (int d = 1; d < 64; d <<= 1) {
        int xup = __shfl_up(s, d, 64);
        s += (lanei >= d) ? xup : 0;
    }
    if (lanei == 63) wpart[threadIdx.x >> 6] = s;
    __syncthreads();
    int offw = 0;
#pragma unroll
    for (int ww = 0; ww < BS / 64; ++ww)
        offw += (ww < (threadIdx.x >> 6)) ? wpart[ww] : 0;
    int ex = offw + s - v;                // exclusive prefix
    if (threadIdx.x < NBUCK) {
        lstart[threadIdx.x] = ex;
        cursor[threadIdx.x] = ex;
        // reserve a contiguous range in this bucket's segment
        gbase[threadIdx.x] = atomicAdd(&gcur[r * NBUCK + threadIdx.x], v);
    }
    __syncthreads();
    // local scatter into LDS (bucket-ordered)
    for (int i = threadIdx.x; i < n; i += BS) {
        int d = dstp[e0 + i];
        int b = d >> SH;
        int pos = atomicAdd(&cursor[b], 1);
        shuf[pos] = ((d & (BSPAN - 1)) << 17) | srcp[e0 + i];   // src < 2^17
        bkt[pos]  = (unsigned char)b;
    }
    __syncthreads();
    // coalesced emission into CAP-strided bucket segments
    for (int i = threadIdx.x; i < n; i += BS) {
        int b = bkt[i];
        int pos = gbase[b] + (i - lstart[b]);
        if (pos < CAP)
            binned[(size_t)(r * NBUCK + b) * CAP + pos] = shuf[i];
    }
}

// ---------------- per-bucket in-LDS counting sort (in place) + CSR + dinv ---
__global__ __launch_bounds__(BSPAN)
void k_sort3(const int* __restrict__ gcur, int* __restrict__ binned,
             int* __restrict__ off, int* __restrict__ cnt,
             float* __restrict__ dinv) {
    __shared__ int shuf[CAP];                       // 35.8 KB
    __shared__ int hist[BSPAN], cur[BSPAN];         // 4 KB
    __shared__ int wpart[BSPAN / 64];
    int gb = blockIdx.x;
    int r = gb / NBUCK, b = gb - r * NBUCK;
    int n = min(gcur[gb], CAP);
    int base = gb * CAP;
    int tid = threadIdx.x;            // 0..511
    hist[tid] = 0;
    for (int i = tid; i < n; i += BSPAN) shuf[i] = binned[base + i];  // coalesced
    __syncthreads();
    for (int i = tid; i < n; i += BSPAN)
        atomicAdd(&hist[((unsigned)shuf[i]) >> 17], 1);
    __syncthreads();
    int v = hist[tid];
    // wave shfl scan + cross-wave pass (R12: 2 barriers vs 18)
    int lanei = tid & 63;
    int s = v;
#pragma unroll
    for (int d = 1; d < 64; d <<= 1) {
        int xup = __shfl_up(s, d, 64);
        s += (lanei >= d) ? xup : 0;
    }
    if (lanei == 63) wpart[tid >> 6] = s;
    __syncthreads();
    int offw = 0;
#pragma unroll
    for (int ww = 0; ww < BSPAN / 64; ++ww)
        offw += (ww < (tid >> 6)) ? wpart[ww] : 0;
    int ex = offw + s - v;                // exclusive prefix
    cur[tid] = ex;
    int node = (b << SH) + tid;
    if (node < N) {
        int ri = r * N + node;
        off[ri] = base + ex;
        cnt[ri] = v;
        dinv[ri] = rsqrtf((float)v + 1.0f);
    }
    __syncthreads();
    // scatter src back over binned, sorted by node (reads from LDS only)
    for (int i = tid; i < n; i += BSPAN) {
        int rc = shuf[i];
        int pos = atomicAdd(&cur[((unsigned)rc) >> 17], 1);
        binned[base + pos] = rc & 0x1FFFF;
    }
}

// ------- Hsc[ri] = dinv[ri]*H0[i] (fp16, + zero row at M) + fixed prefix ----
// R13: also copy the first FIX sorted sources to fixedsrc[ri*FIX..] so k_l1/
// k_l2 can load window 0 from a statically-computed address.
__global__ void k_scale(const float* __restrict__ dinv, const half8* __restrict__ H0h,
                        half8* __restrict__ Hsc, const int* __restrict__ off,
                        const int* __restrict__ cnt, const int* __restrict__ binned,
                        int* __restrict__ fixedsrc) {
    int t = blockIdx.x * blockDim.x + threadIdx.x;
    if (t >= (M + 1) * 4) return;
    int ri = t >> 2, c = t & 3;
    half8 o;
    if (ri == M) {
#pragma unroll
        for (int kk = 0; kk < 8; ++kk) o[kk] = (_Float16)0.f;
    } else {
        int i = ri % N;
        float di = dinv[ri];
        half8 h = H0h[i * 4 + c];
#pragma unroll
        for (int kk = 0; kk < 8; ++kk) o[kk] = (_Float16)(di * (float)h[kk]);
        // fixed adjacency prefix: 4 ints per lane, element-predicated
        int base = off[ri];
        int nn = min(cnt[ri], FIX);
        const int* bp = binned + base + c * 4;
        int4 w;
        w.x = (c * 4 + 0 < nn) ? bp[0] : 0;
        w.y = (c * 4 + 1 < nn) ? bp[1] : 0;
        w.z = (c * 4 + 2 < nn) ? bp[2] : 0;
        w.w = (c * 4 + 3 < nn) ? bp[3] : 0;
        ((int4*)(fixedsrc + (size_t)ri * FIX))[c] = w;   // 16B, coalesced
    }
    Hsc[t] = o;
}

// ---------------- layer 1: 16 lanes/node, 4 lanes/record, pure add-gather --
// R13: window 0 sources come from fixedsrc (static address -> loads at kernel
// entry, chain = fixed->gather = 2 hops). Window 1 ssrc prefetched before
// window-0 processing so the 3-hop tail overlaps.
__global__ void k_l1(const int* __restrict__ off, const int* __restrict__ cnt,
                     const int* __restrict__ ssrc, const int* __restrict__ fixedsrc,
                     const float* __restrict__ dinv, const half8* __restrict__ Hsc,
                     const float* __restrict__ b1, const float* __restrict__ wrowbuf,
                     float* __restrict__ q) {
    int t = blockIdx.x * blockDim.x + threadIdx.x;
    int ri = t >> 4;
    if (ri >= M) return;
    int lane = t & 15;
    int c   = lane & 3;        // 16B chunk of the 64B row
    int sub = lane >> 2;       // record slot 0..3
    int i = ri % N;
    int rbase = ri - i;
    float di = dinv[ri];
    int n = cnt[ri];
    int fs = fixedsrc[(size_t)ri * FIX + lane];    // STATIC addr: issues now
    int base = off[ri];
    half2v acc[4];
    half2v zz = {(_Float16)0.f, (_Float16)0.f};
#pragma unroll
    for (int kk = 0; kk < 4; ++kk) acc[kk] = zz;

    auto procwin = [&](int sbv, int m) {
        for (int bq = 0; bq < 4 && bq * 4 < m; ++bq) {
            int slot = bq * 4 + sub;
            int sj = __shfl(sbv, slot, 16);
            int idx = (slot < m) ? (rbase + sj) : M;   // zero row for pad slots
            half8 h = Hsc[(size_t)idx * 4 + c];
#pragma unroll
            for (int kk = 0; kk < 4; ++kk) {
                half2v hp = {h[2 * kk], h[2 * kk + 1]};
                acc[kk] = acc[kk] + hp;         // v_pk_add_f16
            }
        }
    };

    // prefetch window 1 before processing window 0
    int sb = (16 + lane < n) ? ssrc[base + 16 + lane] : 0;
    procwin(fs, n);                                 // window 0 (from fixed)
    for (int k0 = 16; k0 < n; k0 += 16) {
        int sbn = (k0 + 16 + lane < n) ? ssrc[base + k0 + 16 + lane] : 0;
        procwin(sb, n - k0);
        sb = sbn;
    }
    // packed reduction over record slots (lanes c, c+4, c+8, c+12 same chunk)
#pragma unroll
    for (int o = 4; o <= 8; o <<= 1) {
#pragma unroll
        for (int kk = 0; kk < 4; ++kk) {
            int av = __builtin_bit_cast(int, acc[kk]);
            av = __shfl_xor(av, o, 16);
            acc[kk] = acc[kk] + __builtin_bit_cast(half2v, av);  // v_pk_add_f16
        }
    }
    // self term: + Hsc[ri]  (h1 = di*(sum_src + self) + b1)
    half8 hs = Hsc[(size_t)ri * 4 + c];
#pragma unroll
    for (int kk = 0; kk < 4; ++kk) {
        half2v hp = {hs[2 * kk], hs[2 * kk + 1]};
        acc[kk] = acc[kk] + hp;
    }
    // epilogue: h1 = relu(di*acc + b1); p = h1 . wrow
    float p = 0.f;
#pragma unroll
    for (int kk = 0; kk < 8; ++kk) {
        float av = (float)acc[kk >> 1][kk & 1];
        int j = c * 8 + kk;
        float h1 = fmaf(di, av, b1[j]);
        h1 = fmaxf(h1, 0.f);
        p = fmaf(h1, wrowbuf[j], p);
    }
    p += __shfl_xor(p, 1, 16);
    p += __shfl_xor(p, 2, 16);
    if (lane == 0) q[ri] = di * p;              // q = dinv * g
}

// ---------------- layer 2: per-lane scalar gathers of q + finalize ----------
// R13: first 16 sources from fixedsrc (static address, 2-hop chain).
__global__ void k_l2(const int* __restrict__ off, const int* __restrict__ cnt,
                     const int* __restrict__ ssrc, const int* __restrict__ fixedsrc,
                     const float* __restrict__ dinv, const float* __restrict__ q,
                     const float* __restrict__ wrowbuf, float* __restrict__ out) {
    int t = blockIdx.x * blockDim.x + threadIdx.x;
    int ri = t >> 3;
    if (ri >= M) return;
    int lane = t & 7;
    int i = ri % N;
    int rbase = ri - i;
    int n = cnt[ri];
    int f0 = fixedsrc[(size_t)ri * FIX + lane];        // static addr
    int f1 = fixedsrc[(size_t)ri * FIX + 8 + lane];    // static addr
    int base = off[ri];
    float val = 0.f;
    if (lane < n)     val += q[rbase + f0];
    if (8 + lane < n) val += q[rbase + f1];
    for (int idx = 16 + lane; idx < n; idx += 8) {
        int s = ssrc[base + idx];               // coalesced
        val += q[rbase + s];                    // 4B gather, 1.6MB L2-resident
    }
#pragma unroll
    for (int o = 4; o > 0; o >>= 1) val += __shfl_xor(val, o, 8);
    if (lane == 0)
        out[ri] = dinv[ri] * (val + q[ri]) + wrowbuf[HID];
}

extern "C" void kernel_launch(void* const* d_in, const int* in_sizes, int n_in,
                              void* d_out, int out_size, void* d_ws, size_t ws_size,
                              hipStream_t stream) {
    const float* x  = (const float*)d_in[0];
    const int*  eis = (const int*)d_in[1];
    const float* W1 = (const float*)d_in[2];
    const float* b1 = (const float*)d_in[3];
    const float* W2 = (const float*)d_in[4];
    const float* b2 = (const float*)d_in[5];
    float* out = (float*)d_out;

    // ws (4B units): H0h [N*16] | dinv [M] | q [M] | off [M] | cnt [M] |
    //   wrowbuf [64] | gcur [RB] | binned [RB*CAP] | Hsc [(M+1)*16] |
    //   fixedsrc [M*FIX]  -> ~92 MB
    _Float16* H0h = (_Float16*)d_ws;
    float* dinv   = (float*)d_ws + (size_t)N * HID / 2;
    float* q      = dinv + M;
    int*   off    = (int*)(q + M);
    int*   cnt    = off + M;
    float* wrowbuf = (float*)(cnt + M);
    int*   gcur   = (int*)(wrowbuf + 64);
    int*   binned = gcur + RB;
    _Float16* Hsc = (_Float16*)(binned + (size_t)RB * CAP);
    int* fixedsrc = (int*)(Hsc + (size_t)(M + 1) * HID);

    k_gemm_h0<<<(N * 4 + BS - 1) / BS, BS, 0, stream>>>(x, W1, H0h);
    k_wrow  <<<1, 64, 0, stream>>>(W2, b2, wrowbuf);
    hipMemsetAsync(gcur, 0, (size_t)RB * sizeof(int), stream);
    k_scat2 <<<R * NBKr, BS, 0, stream>>>(eis, gcur, binned);
    k_sort3 <<<RB, BSPAN, 0, stream>>>(gcur, binned, off, cnt, dinv);
    k_scale <<<((M + 1) * 4 + BS - 1) / BS, BS, 0, stream>>>(dinv, (const half8*)H0h,
                                                             (half8*)Hsc, off, cnt,
                                                             binned, fixedsrc);
    k_l1    <<<(M * 16 + BS - 1) / BS, BS, 0, stream>>>(off, cnt, binned, fixedsrc,
                                                        dinv, (const half8*)Hsc, b1,
                                                        wrowbuf, q);
    k_l2    <<<(M * 8 + BS - 1) / BS, BS, 0, stream>>>(off, cnt, binned, fixedsrc,
                                                       dinv, q, wrowbuf, out);
}

// Round 5
// 371.358 us; speedup vs baseline: 1.0925x; 1.0925x over previous
//
#include <hip/hip_runtime.h>

// EdgeFeatGAE: 2-layer GCN (R=4 relations share x, W1, W2), out = sum over
// embed dim -> [R, N].
// Algebra: layer2 collapses to scalar per node (wrow[j] = sum_k W2[j][k]);
// H0 = x@W1 is relation-independent; q[i] = dinv_i * g_i makes layer2 a pure
// scalar gather: out_i = dinv_i*(sum_src q[src] + q[i]) + sum(b2).
// R3: radix-partition into 512-node dst buckets (coalesced writes).
// R5: pack 16 records per wave gather instr (4 lanes x 16B fp16 row chunks),
// exact CSR via per-bucket counting sort, register accumulation. 1738->510us.
// R6/7: k_gemm_h0 vectorized (scalar-load-issue bound). 510->481us.
// R8: dynamic bucket cursors kill hist+scan kernels; in-LDS sort. 481->467us.
// R9: k_scat2 occupancy: CH 8192->4096 -> 6 blocks/CU. 467->436us.
// R10: packed-fp16 acc FAILED (latency-bound, cvt on dep chain). 434us.
// R11: k_l1 fp32 acc, 16 lanes/node -> 4 node-chains/wave. 436->399us.
// R12: pre-scaled rows Hsc = dinv*H0 (fp16): layer1 = pure add-gather,
// packed v_pk_add_f16 acc. k_l1 86.5->75.4us, VALUBusy 37% (latency-exposed).
// R13: fixedsrc prefix (k_l1 chain 3->2 hops; k_l1 dropped below scat2) +
// gemm_h0 shuffle-quarter (x 204->51MB). Net +14us (k_scale grew) but
// profile now exposes k_scat2 = 78us, VALU 6.6%, HBM 11%, occ 40%: pure
// stall. Its loops are [global load -> dependent LDS atomic] one-at-a-time
// (runtime trip count -> no unroll -> 1 load in flight), and dstp is read
// twice.
// R14: register-batch k_scat2: unrolled up-front load of 16 dst + 16 src
// per thread (32 loads in flight, one latency hit), hist/scatter/emission
// run from registers, dstp read once. VGPR 8->~48 (free: LDS-capped occ).

constexpr int N    = 100000;
constexpr int E    = 1600000;
constexpr int R    = 4;
constexpr int FEAT = 128;
constexpr int HID  = 32;
constexpr int EMB  = 16;
constexpr int M    = R * N;
constexpr int BS   = 256;
constexpr int SH    = 9;                          // bucket = dst >> 9
constexpr int BSPAN = 1 << SH;                    // 512 nodes per bucket
constexpr int NBUCK = (N + BSPAN - 1) / BSPAN;    // 196 buckets per relation
constexpr int CH    = 4096;                       // edges per partition block (R9)
constexpr int EPT   = CH / BS;                    // 16 edges per thread
constexpr int NBKr  = (E + CH - 1) / CH;          // 391 blocks per relation
constexpr int RB    = R * NBUCK;                  // 784 buckets total
constexpr int CAP   = 8960;                       // bucket capacity (mean 8192 + 8.5 sigma)
constexpr int FIX   = 16;                         // fixed adjacency prefix (R13)

typedef _Float16 half8 __attribute__((ext_vector_type(8)));   // 16B chunk
typedef _Float16 half2v __attribute__((ext_vector_type(2)));  // packed pair

// ---------------- H0 = x @ W1  [N,32] -> fp16 ----------------
// R13: 4 threads/node, each loads ONE 128B quarter of the x row; k-values
// exchanged via width-4 shuffles. x traffic 204MB -> 51MB.
__global__ void k_gemm_h0(const float* __restrict__ x, const float* __restrict__ W1,
                          _Float16* __restrict__ H0h) {
    int t = blockIdx.x * blockDim.x + threadIdx.x;
    if (t >= N * 4) return;
    int i = t >> 2;            // node
    int qd = t & 3;            // quarter owned + j-octet: j = qd*8
    const float4* xq = (const float4*)(x + (size_t)i * FEAT + qd * 32);
    float4 xv[8];
#pragma unroll
    for (int m = 0; m < 8; ++m) xv[m] = xq[m];    // own 128B quarter
    float acc[8];
#pragma unroll
    for (int kk = 0; kk < 8; ++kk) acc[kk] = 0.f;
#pragma unroll
    for (int qq = 0; qq < 4; ++qq) {              // source quarter
#pragma unroll
        for (int m = 0; m < 8; ++m) {
            float4 v = xv[m];
            float xs[4];
            xs[0] = __shfl(v.x, qq, 4);
            xs[1] = __shfl(v.y, qq, 4);
            xs[2] = __shfl(v.z, qq, 4);
            xs[3] = __shfl(v.w, qq, 4);
            const float* wb = W1 + (qq * 32 + m * 4) * HID + (qd << 3);
#pragma unroll
            for (int dk = 0; dk < 4; ++dk) {
                float4 wlo = *(const float4*)(wb + dk * HID);
                float4 whi = *(const float4*)(wb + dk * HID + 4);
                acc[0] = fmaf(xs[dk], wlo.x, acc[0]);
                acc[1] = fmaf(xs[dk], wlo.y, acc[1]);
                acc[2] = fmaf(xs[dk], wlo.z, acc[2]);
                acc[3] = fmaf(xs[dk], wlo.w, acc[3]);
                acc[4] = fmaf(xs[dk], whi.x, acc[4]);
                acc[5] = fmaf(xs[dk], whi.y, acc[5]);
                acc[6] = fmaf(xs[dk], whi.z, acc[6]);
                acc[7] = fmaf(xs[dk], whi.w, acc[7]);
            }
        }
    }
    half8 hv;
#pragma unroll
    for (int kk = 0; kk < 8; ++kk) hv[kk] = (_Float16)acc[kk];
    ((half8*)H0h)[i * 4 + qd] = hv;    // 16B store, coalesced across lanes
}

// ---------------- wrow[j] = sum_k W2[j][k]; wrowbuf[32] = sum(b2) ----------
__global__ void k_wrow(const float* __restrict__ W2, const float* __restrict__ b2,
                       float* __restrict__ wrowbuf) {
    int j = threadIdx.x;
    if (j < HID) {
        float s = 0.f;
#pragma unroll
        for (int k = 0; k < EMB; ++k) s += W2[j * EMB + k];
        wrowbuf[j] = s;
    } else if (j == HID) {
        float s = 0.f;
#pragma unroll
        for (int k = 0; k < EMB; ++k) s += b2[k];
        wrowbuf[HID] = s;
    }
}

// ---------------- partition: register-batched loads (R14) ------------------
__global__ void k_scat2(const int* __restrict__ eis, int* __restrict__ gcur,
                        int* __restrict__ binned) {
    __shared__ int hist[NBUCK], lstart[NBUCK], cursor[NBUCK], gbase[NBUCK];
    __shared__ int wpart[BS / 64];
    __shared__ int shuf[CH];              // 16 KB (R9)
    __shared__ unsigned char bkt[CH];     // 4 KB
    int r = blockIdx.x / NBKr, k = blockIdx.x - r * NBKr;
    const int* srcp = eis + (size_t)r * 2 * E;
    const int* dstp = srcp + E;
    int e0 = k * CH, n = min(CH, E - e0);
    int tid = threadIdx.x;

    // R14: batch all global loads up-front into registers (unrolled ->
    // all 32 loads in flight; one latency exposure instead of ~32).
    int dreg[EPT], sreg[EPT];
    if (n == CH) {
#pragma unroll
        for (int u = 0; u < EPT; ++u) {
            dreg[u] = dstp[e0 + tid + u * BS];
            sreg[u] = srcp[e0 + tid + u * BS];
        }
    } else {
#pragma unroll
        for (int u = 0; u < EPT; ++u) {
            int i = tid + u * BS;
            dreg[u] = (i < n) ? dstp[e0 + i] : -1;   // sentinel
            sreg[u] = (i < n) ? srcp[e0 + i] : 0;
        }
    }
    for (int b = tid; b < NBUCK; b += BS) hist[b] = 0;
    __syncthreads();
#pragma unroll
    for (int u = 0; u < EPT; ++u)
        if (dreg[u] >= 0) atomicAdd(&hist[dreg[u] >> SH], 1);
    __syncthreads();
    // exclusive prefix over NBUCK (<= BS) entries: wave shfl scan (R12)
    int v = (tid < NBUCK) ? hist[tid] : 0;
    int lanei = tid & 63;
    int s = v;
#pragma unroll
    for (int d = 1; d < 64; d <<= 1) {
        int xup = __shfl_up(s, d, 64);
        s += (lanei >= d) ? xup : 0;
    }
    if (lanei == 63) wpart[tid >> 6] = s;
    __syncthreads();
    int offw = 0;
#pragma unroll
    for (int ww = 0; ww < BS / 64; ++ww)
        offw += (ww < (tid >> 6)) ? wpart[ww] : 0;
    int ex = offw + s - v;                // exclusive prefix
    if (tid < NBUCK) {
        lstart[tid] = ex;
        cursor[tid] = ex;
        // reserve a contiguous range in this bucket's segment
        gbase[tid] = atomicAdd(&gcur[r * NBUCK + tid], v);
    }
    __syncthreads();
    // local scatter into LDS (bucket-ordered), from registers
#pragma unroll
    for (int u = 0; u < EPT; ++u) {
        int d = dreg[u];
        if (d >= 0) {
            int b = d >> SH;
            int pos = atomicAdd(&cursor[b], 1);
            shuf[pos] = ((d & (BSPAN - 1)) << 17) | sreg[u];   // src < 2^17
            bkt[pos]  = (unsigned char)b;
        }
    }
    __syncthreads();
    // coalesced emission into CAP-strided bucket segments
    for (int i = tid; i < n; i += BS) {
        int b = bkt[i];
        int pos = gbase[b] + (i - lstart[b]);
        if (pos < CAP)
            binned[(size_t)(r * NBUCK + b) * CAP + pos] = shuf[i];
    }
}

// ---------------- per-bucket in-LDS counting sort (in place) + CSR + dinv ---
__global__ __launch_bounds__(BSPAN)
void k_sort3(const int* __restrict__ gcur, int* __restrict__ binned,
             int* __restrict__ off, int* __restrict__ cnt,
             float* __restrict__ dinv) {
    __shared__ int shuf[CAP];                       // 35.8 KB
    __shared__ int hist[BSPAN], cur[BSPAN];         // 4 KB
    __shared__ int wpart[BSPAN / 64];
    int gb = blockIdx.x;
    int r = gb / NBUCK, b = gb - r * NBUCK;
    int n = min(gcur[gb], CAP);
    int base = gb * CAP;
    int tid = threadIdx.x;            // 0..511
    hist[tid] = 0;
    for (int i = tid; i < n; i += BSPAN) shuf[i] = binned[base + i];  // coalesced
    __syncthreads();
    for (int i = tid; i < n; i += BSPAN)
        atomicAdd(&hist[((unsigned)shuf[i]) >> 17], 1);
    __syncthreads();
    int v = hist[tid];
    // wave shfl scan + cross-wave pass (R12: 2 barriers vs 18)
    int lanei = tid & 63;
    int s = v;
#pragma unroll
    for (int d = 1; d < 64; d <<= 1) {
        int xup = __shfl_up(s, d, 64);
        s += (lanei >= d) ? xup : 0;
    }
    if (lanei == 63) wpart[tid >> 6] = s;
    __syncthreads();
    int offw = 0;
#pragma unroll
    for (int ww = 0; ww < BSPAN / 64; ++ww)
        offw += (ww < (tid >> 6)) ? wpart[ww] : 0;
    int ex = offw + s - v;                // exclusive prefix
    cur[tid] = ex;
    int node = (b << SH) + tid;
    if (node < N) {
        int ri = r * N + node;
        off[ri] = base + ex;
        cnt[ri] = v;
        dinv[ri] = rsqrtf((float)v + 1.0f);
    }
    __syncthreads();
    // scatter src back over binned, sorted by node (reads from LDS only)
    for (int i = tid; i < n; i += BSPAN) {
        int rc = shuf[i];
        int pos = atomicAdd(&cur[((unsigned)rc) >> 17], 1);
        binned[base + pos] = rc & 0x1FFFF;
    }
}

// ------- Hsc[ri] = dinv[ri]*H0[i] (fp16, + zero row at M) + fixed prefix ----
// R13: also copy the first FIX sorted sources to fixedsrc[ri*FIX..] so k_l1/
// k_l2 can load window 0 from a statically-computed address.
__global__ void k_scale(const float* __restrict__ dinv, const half8* __restrict__ H0h,
                        half8* __restrict__ Hsc, const int* __restrict__ off,
                        const int* __restrict__ cnt, const int* __restrict__ binned,
                        int* __restrict__ fixedsrc) {
    int t = blockIdx.x * blockDim.x + threadIdx.x;
    if (t >= (M + 1) * 4) return;
    int ri = t >> 2, c = t & 3;
    half8 o;
    if (ri == M) {
#pragma unroll
        for (int kk = 0; kk < 8; ++kk) o[kk] = (_Float16)0.f;
    } else {
        int i = ri % N;
        float di = dinv[ri];
        half8 h = H0h[i * 4 + c];
#pragma unroll
        for (int kk = 0; kk < 8; ++kk) o[kk] = (_Float16)(di * (float)h[kk]);
        // fixed adjacency prefix: 4 ints per lane, element-predicated
        int base = off[ri];
        int nn = min(cnt[ri], FIX);
        const int* bp = binned + base + c * 4;
        int4 w;
        w.x = (c * 4 + 0 < nn) ? bp[0] : 0;
        w.y = (c * 4 + 1 < nn) ? bp[1] : 0;
        w.z = (c * 4 + 2 < nn) ? bp[2] : 0;
        w.w = (c * 4 + 3 < nn) ? bp[3] : 0;
        ((int4*)(fixedsrc + (size_t)ri * FIX))[c] = w;   // 16B, coalesced
    }
    Hsc[t] = o;
}

// ---------------- layer 1: 16 lanes/node, 4 lanes/record, pure add-gather --
// R13: window 0 sources come from fixedsrc (static address -> loads at kernel
// entry, chain = fixed->gather = 2 hops). Window 1 ssrc prefetched before
// window-0 processing so the 3-hop tail overlaps.
__global__ void k_l1(const int* __restrict__ off, const int* __restrict__ cnt,
                     const int* __restrict__ ssrc, const int* __restrict__ fixedsrc,
                     const float* __restrict__ dinv, const half8* __restrict__ Hsc,
                     const float* __restrict__ b1, const float* __restrict__ wrowbuf,
                     float* __restrict__ q) {
    int t = blockIdx.x * blockDim.x + threadIdx.x;
    int ri = t >> 4;
    if (ri >= M) return;
    int lane = t & 15;
    int c   = lane & 3;        // 16B chunk of the 64B row
    int sub = lane >> 2;       // record slot 0..3
    int i = ri % N;
    int rbase = ri - i;
    float di = dinv[ri];
    int n = cnt[ri];
    int fs = fixedsrc[(size_t)ri * FIX + lane];    // STATIC addr: issues now
    int base = off[ri];
    half2v acc[4];
    half2v zz = {(_Float16)0.f, (_Float16)0.f};
#pragma unroll
    for (int kk = 0; kk < 4; ++kk) acc[kk] = zz;

    auto procwin = [&](int sbv, int m) {
        for (int bq = 0; bq < 4 && bq * 4 < m; ++bq) {
            int slot = bq * 4 + sub;
            int sj = __shfl(sbv, slot, 16);
            int idx = (slot < m) ? (rbase + sj) : M;   // zero row for pad slots
            half8 h = Hsc[(size_t)idx * 4 + c];
#pragma unroll
            for (int kk = 0; kk < 4; ++kk) {
                half2v hp = {h[2 * kk], h[2 * kk + 1]};
                acc[kk] = acc[kk] + hp;         // v_pk_add_f16
            }
        }
    };

    // prefetch window 1 before processing window 0
    int sb = (16 + lane < n) ? ssrc[base + 16 + lane] : 0;
    procwin(fs, n);                                 // window 0 (from fixed)
    for (int k0 = 16; k0 < n; k0 += 16) {
        int sbn = (k0 + 16 + lane < n) ? ssrc[base + k0 + 16 + lane] : 0;
        procwin(sb, n - k0);
        sb = sbn;
    }
    // packed reduction over record slots (lanes c, c+4, c+8, c+12 same chunk)
#pragma unroll
    for (int o = 4; o <= 8; o <<= 1) {
#pragma unroll
        for (int kk = 0; kk < 4; ++kk) {
            int av = __builtin_bit_cast(int, acc[kk]);
            av = __shfl_xor(av, o, 16);
            acc[kk] = acc[kk] + __builtin_bit_cast(half2v, av);  // v_pk_add_f16
        }
    }
    // self term: + Hsc[ri]  (h1 = di*(sum_src + self) + b1)
    half8 hs = Hsc[(size_t)ri * 4 + c];
#pragma unroll
    for (int kk = 0; kk < 4; ++kk) {
        half2v hp = {hs[2 * kk], hs[2 * kk + 1]};
        acc[kk] = acc[kk] + hp;
    }
    // epilogue: h1 = relu(di*acc + b1); p = h1 . wrow
    float p = 0.f;
#pragma unroll
    for (int kk = 0; kk < 8; ++kk) {
        float av = (float)acc[kk >> 1][kk & 1];
        int j = c * 8 + kk;
        float h1 = fmaf(di, av, b1[j]);
        h1 = fmaxf(h1, 0.f);
        p = fmaf(h1, wrowbuf[j], p);
    }
    p += __shfl_xor(p, 1, 16);
    p += __shfl_xor(p, 2, 16);
    if (lane == 0) q[ri] = di * p;              // q = dinv * g
}

// ---------------- layer 2: per-lane scalar gathers of q + finalize ----------
// R13: first 16 sources from fixedsrc (static address, 2-hop chain).
__global__ void k_l2(const int* __restrict__ off, const int* __restrict__ cnt,
                     const int* __restrict__ ssrc, const int* __restrict__ fixedsrc,
                     const float* __restrict__ dinv, const float* __restrict__ q,
                     const float* __restrict__ wrowbuf, float* __restrict__ out) {
    int t = blockIdx.x * blockDim.x + threadIdx.x;
    int ri = t >> 3;
    if (ri >= M) return;
    int lane = t & 7;
    int i = ri % N;
    int rbase = ri - i;
    int n = cnt[ri];
    int f0 = fixedsrc[(size_t)ri * FIX + lane];        // static addr
    int f1 = fixedsrc[(size_t)ri * FIX + 8 + lane];    // static addr
    int base = off[ri];
    float val = 0.f;
    if (lane < n)     val += q[rbase + f0];
    if (8 + lane < n) val += q[rbase + f1];
    for (int idx = 16 + lane; idx < n; idx += 8) {
        int s = ssrc[base + idx];               // coalesced
        val += q[rbase + s];                    // 4B gather, 1.6MB L2-resident
    }
#pragma unroll
    for (int o = 4; o > 0; o >>= 1) val += __shfl_xor(val, o, 8);
    if (lane == 0)
        out[ri] = dinv[ri] * (val + q[ri]) + wrowbuf[HID];
}

extern "C" void kernel_launch(void* const* d_in, const int* in_sizes, int n_in,
                              void* d_out, int out_size, void* d_ws, size_t ws_size,
                              hipStream_t stream) {
    const float* x  = (const float*)d_in[0];
    const int*  eis = (const int*)d_in[1];
    const float* W1 = (const float*)d_in[2];
    const float* b1 = (const float*)d_in[3];
    const float* W2 = (const float*)d_in[4];
    const float* b2 = (const float*)d_in[5];
    float* out = (float*)d_out;

    // ws (4B units): H0h [N*16] | dinv [M] | q [M] | off [M] | cnt [M] |
    //   wrowbuf [64] | gcur [RB] | binned [RB*CAP] | Hsc [(M+1)*16] |
    //   fixedsrc [M*FIX]  -> ~92 MB
    _Float16* H0h = (_Float16*)d_ws;
    float* dinv   = (float*)d_ws + (size_t)N * HID / 2;
    float* q      = dinv + M;
    int*   off    = (int*)(q + M);
    int*   cnt    = off + M;
    float* wrowbuf = (float*)(cnt + M);
    int*   gcur   = (int*)(wrowbuf + 64);
    int*   binned = gcur + RB;
    _Float16* Hsc = (_Float16*)(binned + (size_t)RB * CAP);
    int* fixedsrc = (int*)(Hsc + (size_t)(M + 1) * HID);

    k_gemm_h0<<<(N * 4 + BS - 1) / BS, BS, 0, stream>>>(x, W1, H0h);
    k_wrow  <<<1, 64, 0, stream>>>(W2, b2, wrowbuf);
    hipMemsetAsync(gcur, 0, (size_t)RB * sizeof(int), stream);
    k_scat2 <<<R * NBKr, BS, 0, stream>>>(eis, gcur, binned);
    k_sort3 <<<RB, BSPAN, 0, stream>>>(gcur, binned, off, cnt, dinv);
    k_scale <<<((M + 1) * 4 + BS - 1) / BS, BS, 0, stream>>>(dinv, (const half8*)H0h,
                                                             (half8*)Hsc, off, cnt,
                                                             binned, fixedsrc);
    k_l1    <<<(M * 16 + BS - 1) / BS, BS, 0, stream>>>(off, cnt, binned, fixedsrc,
                                                        dinv, (const half8*)Hsc, b1,
                                                        wrowbuf, q);
    k_l2    <<<(M * 8 + BS - 1) / BS, BS, 0, stream>>>(off, cnt, binned, fixedsrc,
                                                       dinv, q, wrowbuf, out);
}

// Round 6
// 335.214 us; speedup vs baseline: 1.2102x; 1.1078x over previous
//
#include <hip/hip_runtime.h>

// EdgeFeatGAE: 2-layer GCN (R=4 relations share x, W1, W2), out = sum over
// embed dim -> [R, N].
// Algebra: layer2 collapses to scalar per node (wrow[j] = sum_k W2[j][k]);
// H0 = x@W1 is relation-independent; q[i] = dinv_i * g_i makes layer2 a pure
// scalar gather: out_i = dinv_i*(sum_src q[src] + q[i]) + sum(b2).
// R3: radix-partition into 512-node dst buckets (coalesced writes).
// R5: pack 16 records per wave gather instr (4 lanes x 16B fp16 row chunks),
// exact CSR via per-bucket counting sort, register accumulation. 1738->510us.
// R6/7: k_gemm_h0 vectorized (scalar-load-issue bound). 510->481us.
// R8: dynamic bucket cursors kill hist+scan kernels; in-LDS sort. 481->467us.
// R9: k_scat2 occupancy: CH 8192->4096 -> 6 blocks/CU. 467->436us.
// R10: packed-fp16 acc FAILED (latency-bound, cvt on dep chain). 434us.
// R11: k_l1 fp32 acc, 16 lanes/node -> 4 node-chains/wave. 436->399us.
// R12: pre-scaled rows Hsc = dinv*H0 (fp16): layer1 = pure add-gather,
// packed v_pk_add_f16 acc. k_l1 86.5->75.4us, VALUBusy 37% (latency-exposed).
// R13: fixedsrc prefix (k_l1 3->2 hops) + gemm_h0 shuffle-quarter (x 204->
// 51MB read). R14: register-batched k_scat2 (32 loads in flight): 406->371us.
// R15: k_gemm_h0 was 75us at VALU 8%/HBM 9%/VGPR 32: the shuffle-quarter
// version couldn't keep xv[8] (32 VGPR) resident -> compiler rematerialized
// loads inside the loop; shfl+L1-reload on every FMA group's critical path.
// Rewrite: wave-uniform W1 (readfirstlane octet -> s_load SMEM, SGPR operands
// in v_fma), lane=node with x staged in LDS (coalesced stage, XOR-swizzled
// float4 columns -> conflict-free ds_read_b128). k-loop = pure LDS+SALU+FMA.

constexpr int N    = 100000;
constexpr int E    = 1600000;
constexpr int R    = 4;
constexpr int FEAT = 128;
constexpr int HID  = 32;
constexpr int EMB  = 16;
constexpr int M    = R * N;
constexpr int BS   = 256;
constexpr int SH    = 9;                          // bucket = dst >> 9
constexpr int BSPAN = 1 << SH;                    // 512 nodes per bucket
constexpr int NBUCK = (N + BSPAN - 1) / BSPAN;    // 196 buckets per relation
constexpr int CH    = 4096;                       // edges per partition block (R9)
constexpr int EPT   = CH / BS;                    // 16 edges per thread
constexpr int NBKr  = (E + CH - 1) / CH;          // 391 blocks per relation
constexpr int RB    = R * NBUCK;                  // 784 buckets total
constexpr int CAP   = 8960;                       // bucket capacity (mean 8192 + 8.5 sigma)
constexpr int FIX   = 16;                         // fixed adjacency prefix (R13)
constexpr int GNB   = 64;                         // nodes per gemm block (R15)
constexpr int XPITCH = 132;                       // LDS row pitch in floats (R15)

typedef _Float16 half8 __attribute__((ext_vector_type(8)));   // 16B chunk
typedef _Float16 half2v __attribute__((ext_vector_type(2)));  // packed pair

// ---------------- H0 = x @ W1  [N,32] -> fp16 ----------------
// R15: lane=node, wave=j-octet (uniform -> W1 via s_load). x staged in LDS
// with XOR-swizzled float4 columns: read bank = 4*((l + (c^((l&7)<<2)))%8)
// spans all 32 banks across 64 lanes -> conflict-free ds_read_b128.
__global__ __launch_bounds__(BS)
void k_gemm_h0(const float* __restrict__ x, const float* __restrict__ W1,
               _Float16* __restrict__ H0h) {
    __shared__ float xs[GNB * XPITCH];            // 33 KB
    int base = blockIdx.x * GNB;
    int tid  = threadIdx.x;
    // stage 64 node rows, coalesced: 8 float4 per thread
#pragma unroll
    for (int u = 0; u < 8; ++u) {
        int f = tid + u * BS;          // float4 index in [64][32]
        int n = f >> 5;                // node in block
        int c = f & 31;                // logical float4 column
        if (base + n < N) {
            float4 v = ((const float4*)(x + (size_t)(base + n) * FEAT))[c];
            int p = c ^ ((n & 7) << 2);            // swizzled column
            *(float4*)&xs[n * XPITCH + p * 4] = v;
        }
    }
    __syncthreads();
    int oct = __builtin_amdgcn_readfirstlane(tid >> 6);   // wave-uniform octet
    int l   = tid & 63;                // node owned by this lane
    int i   = base + l;
    const float* wp = W1 + oct * 8;    // uniform base: W1[k][oct*8+j]
    float acc[8];
#pragma unroll
    for (int kk = 0; kk < 8; ++kk) acc[kk] = 0.f;
#pragma unroll 4
    for (int c = 0; c < 32; ++c) {
        int p = c ^ ((l & 7) << 2);
        float4 xv = *(const float4*)&xs[l * XPITCH + p * 4];
        float xk[4] = {xv.x, xv.y, xv.z, xv.w};
#pragma unroll
        for (int dk = 0; dk < 4; ++dk) {
            const float* wr = wp + (c * 4 + dk) * HID;    // uniform -> s_load
#pragma unroll
            for (int j = 0; j < 8; ++j)
                acc[j] = fmaf(xk[dk], wr[j], acc[j]);
        }
    }
    half8 hv;
#pragma unroll
    for (int kk = 0; kk < 8; ++kk) hv[kk] = (_Float16)acc[kk];
    if (i < N) ((half8*)H0h)[i * 4 + oct] = hv;   // 16B store
}

// ---------------- wrow[j] = sum_k W2[j][k]; wrowbuf[32] = sum(b2) ----------
__global__ void k_wrow(const float* __restrict__ W2, const float* __restrict__ b2,
                       float* __restrict__ wrowbuf) {
    int j = threadIdx.x;
    if (j < HID) {
        float s = 0.f;
#pragma unroll
        for (int k = 0; k < EMB; ++k) s += W2[j * EMB + k];
        wrowbuf[j] = s;
    } else if (j == HID) {
        float s = 0.f;
#pragma unroll
        for (int k = 0; k < EMB; ++k) s += b2[k];
        wrowbuf[HID] = s;
    }
}

// ---------------- partition: register-batched loads (R14) ------------------
__global__ void k_scat2(const int* __restrict__ eis, int* __restrict__ gcur,
                        int* __restrict__ binned) {
    __shared__ int hist[NBUCK], lstart[NBUCK], cursor[NBUCK], gbase[NBUCK];
    __shared__ int wpart[BS / 64];
    __shared__ int shuf[CH];              // 16 KB (R9)
    __shared__ unsigned char bkt[CH];     // 4 KB
    int r = blockIdx.x / NBKr, k = blockIdx.x - r * NBKr;
    const int* srcp = eis + (size_t)r * 2 * E;
    const int* dstp = srcp + E;
    int e0 = k * CH, n = min(CH, E - e0);
    int tid = threadIdx.x;

    // R14: batch all global loads up-front into registers (unrolled ->
    // all 32 loads in flight; one latency exposure instead of ~32).
    int dreg[EPT], sreg[EPT];
    if (n == CH) {
#pragma unroll
        for (int u = 0; u < EPT; ++u) {
            dreg[u] = dstp[e0 + tid + u * BS];
            sreg[u] = srcp[e0 + tid + u * BS];
        }
    } else {
#pragma unroll
        for (int u = 0; u < EPT; ++u) {
            int i = tid + u * BS;
            dreg[u] = (i < n) ? dstp[e0 + i] : -1;   // sentinel
            sreg[u] = (i < n) ? srcp[e0 + i] : 0;
        }
    }
    for (int b = tid; b < NBUCK; b += BS) hist[b] = 0;
    __syncthreads();
#pragma unroll
    for (int u = 0; u < EPT; ++u)
        if (dreg[u] >= 0) atomicAdd(&hist[dreg[u] >> SH], 1);
    __syncthreads();
    // exclusive prefix over NBUCK (<= BS) entries: wave shfl scan (R12)
    int v = (tid < NBUCK) ? hist[tid] : 0;
    int lanei = tid & 63;
    int s = v;
#pragma unroll
    for (int d = 1; d < 64; d <<= 1) {
        int xup = __shfl_up(s, d, 64);
        s += (lanei >= d) ? xup : 0;
    }
    if (lanei == 63) wpart[tid >> 6] = s;
    __syncthreads();
    int offw = 0;
#pragma unroll
    for (int ww = 0; ww < BS / 64; ++ww)
        offw += (ww < (tid >> 6)) ? wpart[ww] : 0;
    int ex = offw + s - v;                // exclusive prefix
    if (tid < NBUCK) {
        lstart[tid] = ex;
        cursor[tid] = ex;
        // reserve a contiguous range in this bucket's segment
        gbase[tid] = atomicAdd(&gcur[r * NBUCK + tid], v);
    }
    __syncthreads();
    // local scatter into LDS (bucket-ordered), from registers
#pragma unroll
    for (int u = 0; u < EPT; ++u) {
        int d = dreg[u];
        if (d >= 0) {
            int b = d >> SH;
            int pos = atomicAdd(&cursor[b], 1);
            shuf[pos] = ((d & (BSPAN - 1)) << 17) | sreg[u];   // src < 2^17
            bkt[pos]  = (unsigned char)b;
        }
    }
    __syncthreads();
    // coalesced emission into CAP-strided bucket segments
    for (int i = tid; i < n; i += BS) {
        int b = bkt[i];
        int pos = gbase[b] + (i - lstart[b]);
        if (pos < CAP)
            binned[(size_t)(r * NBUCK + b) * CAP + pos] = shuf[i];
    }
}

// ---------------- per-bucket in-LDS counting sort (in place) + CSR + dinv ---
__global__ __launch_bounds__(BSPAN)
void k_sort3(const int* __restrict__ gcur, int* __restrict__ binned,
             int* __restrict__ off, int* __restrict__ cnt,
             float* __restrict__ dinv) {
    __shared__ int shuf[CAP];                       // 35.8 KB
    __shared__ int hist[BSPAN], cur[BSPAN];         // 4 KB
    __shared__ int wpart[BSPAN / 64];
    int gb = blockIdx.x;
    int r = gb / NBUCK, b = gb - r * NBUCK;
    int n = min(gcur[gb], CAP);
    int base = gb * CAP;
    int tid = threadIdx.x;            // 0..511
    hist[tid] = 0;
    for (int i = tid; i < n; i += BSPAN) shuf[i] = binned[base + i];  // coalesced
    __syncthreads();
    for (int i = tid; i < n; i += BSPAN)
        atomicAdd(&hist[((unsigned)shuf[i]) >> 17], 1);
    __syncthreads();
    int v = hist[tid];
    // wave shfl scan + cross-wave pass (R12: 2 barriers vs 18)
    int lanei = tid & 63;
    int s = v;
#pragma unroll
    for (int d = 1; d < 64; d <<= 1) {
        int xup = __shfl_up(s, d, 64);
        s += (lanei >= d) ? xup : 0;
    }
    if (lanei == 63) wpart[tid >> 6] = s;
    __syncthreads();
    int offw = 0;
#pragma unroll
    for (int ww = 0; ww < BSPAN / 64; ++ww)
        offw += (ww < (tid >> 6)) ? wpart[ww] : 0;
    int ex = offw + s - v;                // exclusive prefix
    cur[tid] = ex;
    int node = (b << SH) + tid;
    if (node < N) {
        int ri = r * N + node;
        off[ri] = base + ex;
        cnt[ri] = v;
        dinv[ri] = rsqrtf((float)v + 1.0f);
    }
    __syncthreads();
    // scatter src back over binned, sorted by node (reads from LDS only)
    for (int i = tid; i < n; i += BSPAN) {
        int rc = shuf[i];
        int pos = atomicAdd(&cur[((unsigned)rc) >> 17], 1);
        binned[base + pos] = rc & 0x1FFFF;
    }
}

// ------- Hsc[ri] = dinv[ri]*H0[i] (fp16, + zero row at M) + fixed prefix ----
// R13: also copy the first FIX sorted sources to fixedsrc[ri*FIX..] so k_l1/
// k_l2 can load window 0 from a statically-computed address.
__global__ void k_scale(const float* __restrict__ dinv, const half8* __restrict__ H0h,
                        half8* __restrict__ Hsc, const int* __restrict__ off,
                        const int* __restrict__ cnt, const int* __restrict__ binned,
                        int* __restrict__ fixedsrc) {
    int t = blockIdx.x * blockDim.x + threadIdx.x;
    if (t >= (M + 1) * 4) return;
    int ri = t >> 2, c = t & 3;
    half8 o;
    if (ri == M) {
#pragma unroll
        for (int kk = 0; kk < 8; ++kk) o[kk] = (_Float16)0.f;
    } else {
        int i = ri % N;
        float di = dinv[ri];
        half8 h = H0h[i * 4 + c];
#pragma unroll
        for (int kk = 0; kk < 8; ++kk) o[kk] = (_Float16)(di * (float)h[kk]);
        // fixed adjacency prefix: 4 ints per lane, element-predicated
        int base = off[ri];
        int nn = min(cnt[ri], FIX);
        const int* bp = binned + base + c * 4;
        int4 w;
        w.x = (c * 4 + 0 < nn) ? bp[0] : 0;
        w.y = (c * 4 + 1 < nn) ? bp[1] : 0;
        w.z = (c * 4 + 2 < nn) ? bp[2] : 0;
        w.w = (c * 4 + 3 < nn) ? bp[3] : 0;
        ((int4*)(fixedsrc + (size_t)ri * FIX))[c] = w;   // 16B, coalesced
    }
    Hsc[t] = o;
}

// ---------------- layer 1: 16 lanes/node, 4 lanes/record, pure add-gather --
// R13: window 0 sources come from fixedsrc (static address -> loads at kernel
// entry, chain = fixed->gather = 2 hops). Window 1 ssrc prefetched before
// window-0 processing so the 3-hop tail overlaps.
__global__ void k_l1(const int* __restrict__ off, const int* __restrict__ cnt,
                     const int* __restrict__ ssrc, const int* __restrict__ fixedsrc,
                     const float* __restrict__ dinv, const half8* __restrict__ Hsc,
                     const float* __restrict__ b1, const float* __restrict__ wrowbuf,
                     float* __restrict__ q) {
    int t = blockIdx.x * blockDim.x + threadIdx.x;
    int ri = t >> 4;
    if (ri >= M) return;
    int lane = t & 15;
    int c   = lane & 3;        // 16B chunk of the 64B row
    int sub = lane >> 2;       // record slot 0..3
    int i = ri % N;
    int rbase = ri - i;
    float di = dinv[ri];
    int n = cnt[ri];
    int fs = fixedsrc[(size_t)ri * FIX + lane];    // STATIC addr: issues now
    int base = off[ri];
    half2v acc[4];
    half2v zz = {(_Float16)0.f, (_Float16)0.f};
#pragma unroll
    for (int kk = 0; kk < 4; ++kk) acc[kk] = zz;

    auto procwin = [&](int sbv, int m) {
        for (int bq = 0; bq < 4 && bq * 4 < m; ++bq) {
            int slot = bq * 4 + sub;
            int sj = __shfl(sbv, slot, 16);
            int idx = (slot < m) ? (rbase + sj) : M;   // zero row for pad slots
            half8 h = Hsc[(size_t)idx * 4 + c];
#pragma unroll
            for (int kk = 0; kk < 4; ++kk) {
                half2v hp = {h[2 * kk], h[2 * kk + 1]};
                acc[kk] = acc[kk] + hp;         // v_pk_add_f16
            }
        }
    };

    // prefetch window 1 before processing window 0
    int sb = (16 + lane < n) ? ssrc[base + 16 + lane] : 0;
    procwin(fs, n);                                 // window 0 (from fixed)
    for (int k0 = 16; k0 < n; k0 += 16) {
        int sbn = (k0 + 16 + lane < n) ? ssrc[base + k0 + 16 + lane] : 0;
        procwin(sb, n - k0);
        sb = sbn;
    }
    // packed reduction over record slots (lanes c, c+4, c+8, c+12 same chunk)
#pragma unroll
    for (int o = 4; o <= 8; o <<= 1) {
#pragma unroll
        for (int kk = 0; kk < 4; ++kk) {
            int av = __builtin_bit_cast(int, acc[kk]);
            av = __shfl_xor(av, o, 16);
            acc[kk] = acc[kk] + __builtin_bit_cast(half2v, av);  // v_pk_add_f16
        }
    }
    // self term: + Hsc[ri]  (h1 = di*(sum_src + self) + b1)
    half8 hs = Hsc[(size_t)ri * 4 + c];
#pragma unroll
    for (int kk = 0; kk < 4; ++kk) {
        half2v hp = {hs[2 * kk], hs[2 * kk + 1]};
        acc[kk] = acc[kk] + hp;
    }
    // epilogue: h1 = relu(di*acc + b1); p = h1 . wrow
    float p = 0.f;
#pragma unroll
    for (int kk = 0; kk < 8; ++kk) {
        float av = (float)acc[kk >> 1][kk & 1];
        int j = c * 8 + kk;
        float h1 = fmaf(di, av, b1[j]);
        h1 = fmaxf(h1, 0.f);
        p = fmaf(h1, wrowbuf[j], p);
    }
    p += __shfl_xor(p, 1, 16);
    p += __shfl_xor(p, 2, 16);
    if (lane == 0) q[ri] = di * p;              // q = dinv * g
}

// ---------------- layer 2: per-lane scalar gathers of q + finalize ----------
// R13: first 16 sources from fixedsrc (static address, 2-hop chain).
__global__ void k_l2(const int* __restrict__ off, const int* __restrict__ cnt,
                     const int* __restrict__ ssrc, const int* __restrict__ fixedsrc,
                     const float* __restrict__ dinv, const float* __restrict__ q,
                     const float* __restrict__ wrowbuf, float* __restrict__ out) {
    int t = blockIdx.x * blockDim.x + threadIdx.x;
    int ri = t >> 3;
    if (ri >= M) return;
    int lane = t & 7;
    int i = ri % N;
    int rbase = ri - i;
    int n = cnt[ri];
    int f0 = fixedsrc[(size_t)ri * FIX + lane];        // static addr
    int f1 = fixedsrc[(size_t)ri * FIX + 8 + lane];    // static addr
    int base = off[ri];
    float val = 0.f;
    if (lane < n)     val += q[rbase + f0];
    if (8 + lane < n) val += q[rbase + f1];
    for (int idx = 16 + lane; idx < n; idx += 8) {
        int s = ssrc[base + idx];               // coalesced
        val += q[rbase + s];                    // 4B gather, 1.6MB L2-resident
    }
#pragma unroll
    for (int o = 4; o > 0; o >>= 1) val += __shfl_xor(val, o, 8);
    if (lane == 0)
        out[ri] = dinv[ri] * (val + q[ri]) + wrowbuf[HID];
}

extern "C" void kernel_launch(void* const* d_in, const int* in_sizes, int n_in,
                              void* d_out, int out_size, void* d_ws, size_t ws_size,
                              hipStream_t stream) {
    const float* x  = (const float*)d_in[0];
    const int*  eis = (const int*)d_in[1];
    const float* W1 = (const float*)d_in[2];
    const float* b1 = (const float*)d_in[3];
    const float* W2 = (const float*)d_in[4];
    const float* b2 = (const float*)d_in[5];
    float* out = (float*)d_out;

    // ws (4B units): H0h [N*16] | dinv [M] | q [M] | off [M] | cnt [M] |
    //   wrowbuf [64] | gcur [RB] | binned [RB*CAP] | Hsc [(M+1)*16] |
    //   fixedsrc [M*FIX]  -> ~92 MB
    _Float16* H0h = (_Float16*)d_ws;
    float* dinv   = (float*)d_ws + (size_t)N * HID / 2;
    float* q      = dinv + M;
    int*   off    = (int*)(q + M);
    int*   cnt    = off + M;
    float* wrowbuf = (float*)(cnt + M);
    int*   gcur   = (int*)(wrowbuf + 64);
    int*   binned = gcur + RB;
    _Float16* Hsc = (_Float16*)(binned + (size_t)RB * CAP);
    int* fixedsrc = (int*)(Hsc + (size_t)(M + 1) * HID);

    k_gemm_h0<<<(N + GNB - 1) / GNB, BS, 0, stream>>>(x, W1, H0h);
    k_wrow  <<<1, 64, 0, stream>>>(W2, b2, wrowbuf);
    hipMemsetAsync(gcur, 0, (size_t)RB * sizeof(int), stream);
    k_scat2 <<<R * NBKr, BS, 0, stream>>>(eis, gcur, binned);
    k_sort3 <<<RB, BSPAN, 0, stream>>>(gcur, binned, off, cnt, dinv);
    k_scale <<<((M + 1) * 4 + BS - 1) / BS, BS, 0, stream>>>(dinv, (const half8*)H0h,
                                                             (half8*)Hsc, off, cnt,
                                                             binned, fixedsrc);
    k_l1    <<<(M * 16 + BS - 1) / BS, BS, 0, stream>>>(off, cnt, binned, fixedsrc,
                                                        dinv, (const half8*)Hsc, b1,
                                                        wrowbuf, q);
    k_l2    <<<(M * 8 + BS - 1) / BS, BS, 0, stream>>>(off, cnt, binned, fixedsrc,
                                                       dinv, q, wrowbuf, out);
}

// Round 8
// 335.134 us; speedup vs baseline: 1.2105x; 1.0002x over previous
//
#include <hip/hip_runtime.h>

// EdgeFeatGAE: 2-layer GCN (R=4 relations share x, W1, W2), out = sum over
// embed dim -> [R, N].
// Algebra: layer2 collapses to scalar per node (wrow[j] = sum_k W2[j][k]);
// H0 = x@W1 is relation-independent; q[i] = dinv_i * g_i makes layer2 a pure
// scalar gather: out_i = dinv_i*(sum_src q[src] + q[i]) + sum(b2).
// R3: radix-partition into 512-node dst buckets. R5: 16 records per wave
// gather instr, CSR via per-bucket counting sort. 1738->510us.
// R8: in-LDS sort. R9: k_scat2 CH->4096. 467->436us.
// R10: packed-fp16 acc FAILED (latency-bound, cvt on dep chain). 434us.
// R11: k_l1 16 lanes/node -> 4 node-chains/wave. 436->399us.
// R12: pre-scaled rows Hsc = dinv*H0 (fp16): layer1 = pure add-gather,
// packed v_pk_add_f16 acc. k_l1 -> 75us, VALUBusy 37% (latency-exposed).
// R13: fixedsrc prefix (k_l1 3->2 hops) + gemm_h0 shuffle-quarter.
// R14: register-batched k_scat2 (32 loads in flight): scat2 78->sub-70,
// total 406->371us.
// R15: k_gemm_h0 rewrite (wave-uniform W1 via s_load, lane=node, x staged
// in LDS XOR-swizzled): 75->sub-70, total 371->335us.
// R16: k_sort3 register-resident records (18 regs/thr, all loads in
// flight - the R14 pattern) and k_scale DELETED (Hsc scaling + fixedsrc
// prefix fused into sort3's epilogue; first-16 prefix stashed to
// transposed fix_lds during the scatter). Hsc zero row moves to k_wrow.
// R17: R16 bench died with a container-level infra failure (no pytest
// output, no counters). Source audit found no OOB/LDS/race fault; layout
// is byte-identical to R13-R15. Resubmitting unchanged to disambiguate
// infra flake vs kernel fault.

constexpr int N    = 100000;
constexpr int E    = 1600000;
constexpr int R    = 4;
constexpr int FEAT = 128;
constexpr int HID  = 32;
constexpr int EMB  = 16;
constexpr int M    = R * N;
constexpr int BS   = 256;
constexpr int SH    = 9;                          // bucket = dst >> 9
constexpr int BSPAN = 1 << SH;                    // 512 nodes per bucket
constexpr int NBUCK = (N + BSPAN - 1) / BSPAN;    // 196 buckets per relation
constexpr int CH    = 4096;                       // edges per partition block (R9)
constexpr int EPT   = CH / BS;                    // 16 edges per thread
constexpr int NBKr  = (E + CH - 1) / CH;          // 391 blocks per relation
constexpr int RB    = R * NBUCK;                  // 784 buckets total
constexpr int CAP   = 8960;                       // bucket capacity (mean 8192 + 8.5 sigma)
constexpr int SPT   = (CAP + BSPAN - 1) / BSPAN;  // 18 records per sort thread (R16)
constexpr int FIX   = 16;                         // fixed adjacency prefix (R13)
constexpr int GNB   = 64;                         // nodes per gemm block (R15)
constexpr int XPITCH = 132;                       // LDS row pitch in floats (R15)

typedef _Float16 half8 __attribute__((ext_vector_type(8)));   // 16B chunk
typedef _Float16 half2v __attribute__((ext_vector_type(2)));  // packed pair

// ---------------- H0 = x @ W1  [N,32] -> fp16 ----------------
// R15: lane=node, wave=j-octet (uniform -> W1 via s_load). x staged in LDS
// with XOR-swizzled float4 columns -> conflict-free ds_read_b128.
__global__ __launch_bounds__(BS)
void k_gemm_h0(const float* __restrict__ x, const float* __restrict__ W1,
               _Float16* __restrict__ H0h) {
    __shared__ float xs[GNB * XPITCH];            // 33 KB
    int base = blockIdx.x * GNB;
    int tid  = threadIdx.x;
    // stage 64 node rows, coalesced: 8 float4 per thread
#pragma unroll
    for (int u = 0; u < 8; ++u) {
        int f = tid + u * BS;          // float4 index in [64][32]
        int n = f >> 5;                // node in block
        int c = f & 31;                // logical float4 column
        if (base + n < N) {
            float4 v = ((const float4*)(x + (size_t)(base + n) * FEAT))[c];
            int p = c ^ ((n & 7) << 2);            // swizzled column
            *(float4*)&xs[n * XPITCH + p * 4] = v;
        }
    }
    __syncthreads();
    int oct = __builtin_amdgcn_readfirstlane(tid >> 6);   // wave-uniform octet
    int l   = tid & 63;                // node owned by this lane
    int i   = base + l;
    const float* wp = W1 + oct * 8;    // uniform base: W1[k][oct*8+j]
    float acc[8];
#pragma unroll
    for (int kk = 0; kk < 8; ++kk) acc[kk] = 0.f;
#pragma unroll 4
    for (int c = 0; c < 32; ++c) {
        int p = c ^ ((l & 7) << 2);
        float4 xv = *(const float4*)&xs[l * XPITCH + p * 4];
        float xk[4] = {xv.x, xv.y, xv.z, xv.w};
#pragma unroll
        for (int dk = 0; dk < 4; ++dk) {
            const float* wr = wp + (c * 4 + dk) * HID;    // uniform -> s_load
#pragma unroll
            for (int j = 0; j < 8; ++j)
                acc[j] = fmaf(xk[dk], wr[j], acc[j]);
        }
    }
    half8 hv;
#pragma unroll
    for (int kk = 0; kk < 8; ++kk) hv[kk] = (_Float16)acc[kk];
    if (i < N) ((half8*)H0h)[i * 4 + oct] = hv;   // 16B store
}

// -------- wrow[j] = sum_k W2[j][k]; wrowbuf[32] = sum(b2); Hsc zero row ----
__global__ void k_wrow(const float* __restrict__ W2, const float* __restrict__ b2,
                       float* __restrict__ wrowbuf, _Float16* __restrict__ Hsc) {
    int j = threadIdx.x;
    if (j < HID) {
        float s = 0.f;
#pragma unroll
        for (int k = 0; k < EMB; ++k) s += W2[j * EMB + k];
        wrowbuf[j] = s;
    } else if (j == HID) {
        float s = 0.f;
#pragma unroll
        for (int k = 0; k < EMB; ++k) s += b2[k];
        wrowbuf[HID] = s;
    } else if (j >= 34 && j < 50) {
        // R16: Hsc zero row (was k_scale's ri==M branch)
        ((unsigned*)(Hsc + (size_t)M * HID))[j - 34] = 0u;
    }
}

// ---------------- partition: register-batched loads (R14) ------------------
__global__ void k_scat2(const int* __restrict__ eis, int* __restrict__ gcur,
                        int* __restrict__ binned) {
    __shared__ int hist[NBUCK], lstart[NBUCK], cursor[NBUCK], gbase[NBUCK];
    __shared__ int wpart[BS / 64];
    __shared__ int shuf[CH];              // 16 KB (R9)
    __shared__ unsigned char bkt[CH];     // 4 KB
    int r = blockIdx.x / NBKr, k = blockIdx.x - r * NBKr;
    const int* srcp = eis + (size_t)r * 2 * E;
    const int* dstp = srcp + E;
    int e0 = k * CH, n = min(CH, E - e0);
    int tid = threadIdx.x;

    // R14: batch all global loads up-front into registers (unrolled ->
    // all 32 loads in flight; one latency exposure instead of ~32).
    int dreg[EPT], sreg[EPT];
    if (n == CH) {
#pragma unroll
        for (int u = 0; u < EPT; ++u) {
            dreg[u] = dstp[e0 + tid + u * BS];
            sreg[u] = srcp[e0 + tid + u * BS];
        }
    } else {
#pragma unroll
        for (int u = 0; u < EPT; ++u) {
            int i = tid + u * BS;
            dreg[u] = (i < n) ? dstp[e0 + i] : -1;   // sentinel
            sreg[u] = (i < n) ? srcp[e0 + i] : 0;
        }
    }
    for (int b = tid; b < NBUCK; b += BS) hist[b] = 0;
    __syncthreads();
#pragma unroll
    for (int u = 0; u < EPT; ++u)
        if (dreg[u] >= 0) atomicAdd(&hist[dreg[u] >> SH], 1);
    __syncthreads();
    // exclusive prefix over NBUCK (<= BS) entries: wave shfl scan (R12)
    int v = (tid < NBUCK) ? hist[tid] : 0;
    int lanei = tid & 63;
    int s = v;
#pragma unroll
    for (int d = 1; d < 64; d <<= 1) {
        int xup = __shfl_up(s, d, 64);
        s += (lanei >= d) ? xup : 0;
    }
    if (lanei == 63) wpart[tid >> 6] = s;
    __syncthreads();
    int offw = 0;
#pragma unroll
    for (int ww = 0; ww < BS / 64; ++ww)
        offw += (ww < (tid >> 6)) ? wpart[ww] : 0;
    int ex = offw + s - v;                // exclusive prefix
    if (tid < NBUCK) {
        lstart[tid] = ex;
        cursor[tid] = ex;
        // reserve a contiguous range in this bucket's segment
        gbase[tid] = atomicAdd(&gcur[r * NBUCK + tid], v);
    }
    __syncthreads();
    // local scatter into LDS (bucket-ordered), from registers
#pragma unroll
    for (int u = 0; u < EPT; ++u) {
        int d = dreg[u];
        if (d >= 0) {
            int b = d >> SH;
            int pos = atomicAdd(&cursor[b], 1);
            shuf[pos] = ((d & (BSPAN - 1)) << 17) | sreg[u];   // src < 2^17
            bkt[pos]  = (unsigned char)b;
        }
    }
    __syncthreads();
    // coalesced emission into CAP-strided bucket segments
    for (int i = tid; i < n; i += BS) {
        int b = bkt[i];
        int pos = gbase[b] + (i - lstart[b]);
        if (pos < CAP)
            binned[(size_t)(r * NBUCK + b) * CAP + pos] = shuf[i];
    }
}

// ------ per-bucket counting sort (register-resident, R16) + CSR + dinv -----
// ------ + fused Hsc scaling and fixedsrc prefix (was k_scale) --------------
__global__ __launch_bounds__(BSPAN)
void k_sort3(const int* __restrict__ gcur, int* __restrict__ binned,
             int* __restrict__ off, int* __restrict__ cnt,
             float* __restrict__ dinv, const half8* __restrict__ H0h,
             half8* __restrict__ Hsc, int* __restrict__ fixedsrc) {
    __shared__ int fix_lds[FIX * BSPAN];            // 32 KB, transposed [k][node]
    __shared__ int hist[BSPAN], cur[BSPAN], exs[BSPAN];   // 6 KB
    __shared__ int wpart[BSPAN / 64];
    int gb = blockIdx.x;
    int r = gb / NBUCK, b = gb - r * NBUCK;
    int n = min(gcur[gb], CAP);
    int base = gb * CAP;
    int tid = threadIdx.x;            // 0..511
    // R16: all records register-resident; 18 loads in flight, no LDS staging
    int rg[SPT];
#pragma unroll
    for (int u = 0; u < SPT; ++u) {
        int i = tid + u * BSPAN;
        rg[u] = (i < n) ? binned[base + i] : -1;    // values >= 0; -1 sentinel
    }
    hist[tid] = 0;
    __syncthreads();
#pragma unroll
    for (int u = 0; u < SPT; ++u)
        if (rg[u] >= 0) atomicAdd(&hist[((unsigned)rg[u]) >> 17], 1);
    __syncthreads();
    int v = hist[tid];
    // wave shfl scan + cross-wave pass (R12)
    int lanei = tid & 63;
    int s = v;
#pragma unroll
    for (int d = 1; d < 64; d <<= 1) {
        int xup = __shfl_up(s, d, 64);
        s += (lanei >= d) ? xup : 0;
    }
    if (lanei == 63) wpart[tid >> 6] = s;
    __syncthreads();
    int offw = 0;
#pragma unroll
    for (int ww = 0; ww < BSPAN / 64; ++ww)
        offw += (ww < (tid >> 6)) ? wpart[ww] : 0;
    int ex = offw + s - v;                // exclusive prefix
    cur[tid] = ex;
    exs[tid] = ex;
    int node = (b << SH) + tid;
    int ri = r * N + node;
    if (node < N) {
        off[ri] = base + ex;
        cnt[ri] = v;
        dinv[ri] = rsqrtf((float)v + 1.0f);
    }
    __syncthreads();
    // scatter src into binned sorted by node; stash first-FIX into fix_lds
#pragma unroll
    for (int u = 0; u < SPT; ++u) {
        int rc = rg[u];
        if (rc >= 0) {
            int nd = ((unsigned)rc) >> 17;
            int pos = atomicAdd(&cur[nd], 1);
            int val = rc & 0x1FFFF;
            binned[base + pos] = val;
            int k = pos - exs[nd];
            if (k < FIX) fix_lds[k * BSPAN + nd] = val;
        }
    }
    __syncthreads();
    // fused epilogue (was k_scale): fixedsrc prefix + Hsc = dinv*H0 (fp16)
    if (node < N) {
        int nn = min(v, FIX);
#pragma unroll
        for (int cc = 0; cc < 4; ++cc) {
            int4 w;
            w.x = (cc * 4 + 0 < nn) ? fix_lds[(cc * 4 + 0) * BSPAN + tid] : 0;
            w.y = (cc * 4 + 1 < nn) ? fix_lds[(cc * 4 + 1) * BSPAN + tid] : 0;
            w.z = (cc * 4 + 2 < nn) ? fix_lds[(cc * 4 + 2) * BSPAN + tid] : 0;
            w.w = (cc * 4 + 3 < nn) ? fix_lds[(cc * 4 + 3) * BSPAN + tid] : 0;
            ((int4*)(fixedsrc + (size_t)ri * FIX))[cc] = w;   // coalesced 64B
        }
        float di = rsqrtf((float)v + 1.0f);
#pragma unroll
        for (int cc = 0; cc < 4; ++cc) {
            half8 h = H0h[(size_t)node * 4 + cc];             // coalesced 64B
            half8 o;
#pragma unroll
            for (int kk = 0; kk < 8; ++kk) o[kk] = (_Float16)(di * (float)h[kk]);
            Hsc[(size_t)ri * 4 + cc] = o;                     // coalesced 64B
        }
    }
}

// ---------------- layer 1: 16 lanes/node, 4 lanes/record, pure add-gather --
// R13: window 0 sources come from fixedsrc (static address -> loads at kernel
// entry, chain = fixed->gather = 2 hops). Window 1 ssrc prefetched before
// window-0 processing so the 3-hop tail overlaps.
__global__ void k_l1(const int* __restrict__ off, const int* __restrict__ cnt,
                     const int* __restrict__ ssrc, const int* __restrict__ fixedsrc,
                     const float* __restrict__ dinv, const half8* __restrict__ Hsc,
                     const float* __restrict__ b1, const float* __restrict__ wrowbuf,
                     float* __restrict__ q) {
    int t = blockIdx.x * blockDim.x + threadIdx.x;
    int ri = t >> 4;
    if (ri >= M) return;
    int lane = t & 15;
    int c   = lane & 3;        // 16B chunk of the 64B row
    int sub = lane >> 2;       // record slot 0..3
    int i = ri % N;
    int rbase = ri - i;
    float di = dinv[ri];
    int n = cnt[ri];
    int fs = fixedsrc[(size_t)ri * FIX + lane];    // STATIC addr: issues now
    int base = off[ri];
    half2v acc[4];
    half2v zz = {(_Float16)0.f, (_Float16)0.f};
#pragma unroll
    for (int kk = 0; kk < 4; ++kk) acc[kk] = zz;

    auto procwin = [&](int sbv, int m) {
        for (int bq = 0; bq < 4 && bq * 4 < m; ++bq) {
            int slot = bq * 4 + sub;
            int sj = __shfl(sbv, slot, 16);
            int idx = (slot < m) ? (rbase + sj) : M;   // zero row for pad slots
            half8 h = Hsc[(size_t)idx * 4 + c];
#pragma unroll
            for (int kk = 0; kk < 4; ++kk) {
                half2v hp = {h[2 * kk], h[2 * kk + 1]};
                acc[kk] = acc[kk] + hp;         // v_pk_add_f16
            }
        }
    };

    // prefetch window 1 before processing window 0
    int sb = (16 + lane < n) ? ssrc[base + 16 + lane] : 0;
    procwin(fs, n);                                 // window 0 (from fixed)
    for (int k0 = 16; k0 < n; k0 += 16) {
        int sbn = (k0 + 16 + lane < n) ? ssrc[base + k0 + 16 + lane] : 0;
        procwin(sb, n - k0);
        sb = sbn;
    }
    // packed reduction over record slots (lanes c, c+4, c+8, c+12 same chunk)
#pragma unroll
    for (int o = 4; o <= 8; o <<= 1) {
#pragma unroll
        for (int kk = 0; kk < 4; ++kk) {
            int av = __builtin_bit_cast(int, acc[kk]);
            av = __shfl_xor(av, o, 16);
            acc[kk] = acc[kk] + __builtin_bit_cast(half2v, av);  // v_pk_add_f16
        }
    }
    // self term: + Hsc[ri]  (h1 = di*(sum_src + self) + b1)
    half8 hs = Hsc[(size_t)ri * 4 + c];
#pragma unroll
    for (int kk = 0; kk < 4; ++kk) {
        half2v hp = {hs[2 * kk], hs[2 * kk + 1]};
        acc[kk] = acc[kk] + hp;
    }
    // epilogue: h1 = relu(di*acc + b1); p = h1 . wrow
    float p = 0.f;
#pragma unroll
    for (int kk = 0; kk < 8; ++kk) {
        float av = (float)acc[kk >> 1][kk & 1];
        int j = c * 8 + kk;
        float h1 = fmaf(di, av, b1[j]);
        h1 = fmaxf(h1, 0.f);
        p = fmaf(h1, wrowbuf[j], p);
    }
    p += __shfl_xor(p, 1, 16);
    p += __shfl_xor(p, 2, 16);
    if (lane == 0) q[ri] = di * p;              // q = dinv * g
}

// ---------------- layer 2: per-lane scalar gathers of q + finalize ----------
// R13: first 16 sources from fixedsrc (static address, 2-hop chain).
__global__ void k_l2(const int* __restrict__ off, const int* __restrict__ cnt,
                     const int* __restrict__ ssrc, const int* __restrict__ fixedsrc,
                     const float* __restrict__ dinv, const float* __restrict__ q,
                     const float* __restrict__ wrowbuf, float* __restrict__ out) {
    int t = blockIdx.x * blockDim.x + threadIdx.x;
    int ri = t >> 3;
    if (ri >= M) return;
    int lane = t & 7;
    int i = ri % N;
    int rbase = ri - i;
    int n = cnt[ri];
    int f0 = fixedsrc[(size_t)ri * FIX + lane];        // static addr
    int f1 = fixedsrc[(size_t)ri * FIX + 8 + lane];    // static addr
    int base = off[ri];
    float val = 0.f;
    if (lane < n)     val += q[rbase + f0];
    if (8 + lane < n) val += q[rbase + f1];
    for (int idx = 16 + lane; idx < n; idx += 8) {
        int s = ssrc[base + idx];               // coalesced
        val += q[rbase + s];                    // 4B gather, 1.6MB L2-resident
    }
#pragma unroll
    for (int o = 4; o > 0; o >>= 1) val += __shfl_xor(val, o, 8);
    if (lane == 0)
        out[ri] = dinv[ri] * (val + q[ri]) + wrowbuf[HID];
}

extern "C" void kernel_launch(void* const* d_in, const int* in_sizes, int n_in,
                              void* d_out, int out_size, void* d_ws, size_t ws_size,
                              hipStream_t stream) {
    const float* x  = (const float*)d_in[0];
    const int*  eis = (const int*)d_in[1];
    const float* W1 = (const float*)d_in[2];
    const float* b1 = (const float*)d_in[3];
    const float* W2 = (const float*)d_in[4];
    const float* b2 = (const float*)d_in[5];
    float* out = (float*)d_out;

    // ws (4B units): H0h [N*16] | dinv [M] | q [M] | off [M] | cnt [M] |
    //   wrowbuf [64] | gcur [RB] | binned [RB*CAP] | Hsc [(M+1)*16] |
    //   fixedsrc [M*FIX]  -> ~92 MB
    _Float16* H0h = (_Float16*)d_ws;
    float* dinv   = (float*)d_ws + (size_t)N * HID / 2;
    float* q      = dinv + M;
    int*   off    = (int*)(q + M);
    int*   cnt    = off + M;
    float* wrowbuf = (float*)(cnt + M);
    int*   gcur   = (int*)(wrowbuf + 64);
    int*   binned = gcur + RB;
    _Float16* Hsc = (_Float16*)(binned + (size_t)RB * CAP);
    int* fixedsrc = (int*)(Hsc + (size_t)(M + 1) * HID);

    k_gemm_h0<<<(N + GNB - 1) / GNB, BS, 0, stream>>>(x, W1, H0h);
    k_wrow  <<<1, 64, 0, stream>>>(W2, b2, wrowbuf, Hsc);
    hipMemsetAsync(gcur, 0, (size_t)RB * sizeof(int), stream);
    k_scat2 <<<R * NBKr, BS, 0, stream>>>(eis, gcur, binned);
    k_sort3 <<<RB, BSPAN, 0, stream>>>(gcur, binned, off, cnt, dinv,
                                       (const half8*)H0h, (half8*)Hsc, fixedsrc);
    k_l1    <<<(M * 16 + BS - 1) / BS, BS, 0, stream>>>(off, cnt, binned, fixedsrc,
                                                        dinv, (const half8*)Hsc, b1,
                                                        wrowbuf, q);
    k_l2    <<<(M * 8 + BS - 1) / BS, BS, 0, stream>>>(off, cnt, binned, fixedsrc,
                                                       dinv, q, wrowbuf, out);
}